// Round 4
// baseline (297.449 us; speedup 1.0000x reference)
//
#include <hip/hip_runtime.h>
#include <hip/hip_bf16.h>
#include <cmath>

// out[b] = X_b (Wq Wk^T) (X_b^T X_b) / 768^1.5   (47 GF factorized form)
//   P  = Wq * Wk^T                      (fp32 in, bf16 out)
//   G32_b = Xt_b * Xt_b^T               (split-K x4, fp32 atomic accumulate)
//   Ht_b = alpha * G32_b * P^T          (== H^T since G symmetric; bf16 out)
//   out_b = Xbf_b * Ht_b^T              (bf16 A, fp32 out)
// MFMA bf16 16x16x32, 128x128 tile, BK=32, fp32 accumulate.
// LDS row stride 40 shorts (80 B): bank period 8 -> only free 2-way aliasing.

typedef __attribute__((ext_vector_type(8))) short short8;
typedef __attribute__((ext_vector_type(4))) float f32x4;

#define LDST 40  // LDS row stride in shorts (80 B; 16B-aligned for b128)

__device__ __forceinline__ unsigned short f2bf(float f) {
    union { float f; unsigned int u; } v; v.f = f;
    unsigned int u = v.u;
    return (unsigned short)((u + 0x7FFFu + ((u >> 16) & 1u)) >> 16);  // RNE
}

// ---- X[b][S][D] fp32 -> Xt[b][D][S] bf16 AND Xbf[b][S][D] bf16 ----
__global__ __launch_bounds__(256)
void transpose_bf16(const float* __restrict__ X, unsigned short* __restrict__ Xt,
                    unsigned short* __restrict__ Xbf, int S, int D)
{
    __shared__ unsigned short tile[32][36];  // 72 B rows: 8B-aligned ushort4 access
    const int b = blockIdx.z;
    const int s0 = blockIdx.x * 32;
    const int d0 = blockIdx.y * 32;
    const float* Xb = X + (size_t)b * S * D;
    unsigned short* Xtb = Xt + (size_t)b * S * D;
    unsigned short* Xbb = Xbf + (size_t)b * S * D;
    const int tx = threadIdx.x & 7;    // d-group (4 floats)
    const int ty = threadIdx.x >> 3;   // s 0..31

    float4 v = *reinterpret_cast<const float4*>(&Xb[(size_t)(s0 + ty) * D + d0 + tx * 4]);
    ushort4 pk;
    pk.x = f2bf(v.x); pk.y = f2bf(v.y); pk.z = f2bf(v.z); pk.w = f2bf(v.w);
    *reinterpret_cast<ushort4*>(&Xbb[(size_t)(s0 + ty) * D + d0 + tx * 4]) = pk;
    tile[tx * 4 + 0][ty] = pk.x;
    tile[tx * 4 + 1][ty] = pk.y;
    tile[tx * 4 + 2][ty] = pk.z;
    tile[tx * 4 + 3][ty] = pk.w;
    __syncthreads();
    ushort4 o;
    o.x = tile[ty][tx * 4 + 0];
    o.y = tile[ty][tx * 4 + 1];
    o.z = tile[ty][tx * 4 + 2];
    o.w = tile[ty][tx * 4 + 3];
    *reinterpret_cast<ushort4*>(&Xtb[(size_t)(d0 + ty) * S + s0 + tx * 4]) = o;
}

// ---- staging: 128x32 tile (row-major, leading dim ld) into LDS bf16 [128][LDST] ----
__device__ __forceinline__ void stage_tile(const float* src, unsigned short* lds, int ld, int tid)
{
    #pragma unroll
    for (int it = 0; it < 4; ++it) {
        int idx = it * 256 + tid;         // 0..1023
        int r = idx >> 3;                 // 8 threads per row
        int c = (idx & 7) * 4;
        float4 v = *reinterpret_cast<const float4*>(&src[(size_t)r * ld + c]);
        unsigned long long p =
            (unsigned long long)f2bf(v.x)         |
            ((unsigned long long)f2bf(v.y) << 16) |
            ((unsigned long long)f2bf(v.z) << 32) |
            ((unsigned long long)f2bf(v.w) << 48);
        *reinterpret_cast<unsigned long long*>(&lds[r * LDST + c]) = p;
    }
}
__device__ __forceinline__ void stage_tile(const unsigned short* src, unsigned short* lds, int ld, int tid)
{
    #pragma unroll
    for (int it = 0; it < 2; ++it) {
        int idx = it * 256 + tid;         // 0..511
        int r = idx >> 2;                 // 4 threads per row
        int c = (idx & 3) * 8;
        uint4 v = *reinterpret_cast<const uint4*>(&src[(size_t)r * ld + c]);
        *reinterpret_cast<uint4*>(&lds[r * LDST + c]) = v;
    }
}

__device__ __forceinline__ void store_c(float* C, size_t i, float v) { C[i] = v; }
__device__ __forceinline__ void store_c(unsigned short* C, size_t i, float v) { C[i] = f2bf(v); }

// C[M,N] (+)= alpha * A[M,K] * Bt[N,K]^T ; row-major; batched via blockIdx.z.
// blockIdx.z = b * nsplit + sp; split sp covers columns [sp*Kloop, (sp+1)*Kloop) of lda/ldb.
// ATOMIC: accumulate with fp32 atomics (C must be float; zero-init'd by caller).
template <typename AT, typename BT, typename CT, bool ATOMIC>
__global__ __launch_bounds__(256)
void gemm_abt(const AT* __restrict__ Ab, const BT* __restrict__ Bb,
              CT* __restrict__ Cb, int M, int N, int Kloop,
              int lda, int ldb, int ldc,
              long sA, long sB, long sC, int nsplit, float alpha)
{
    const int z = blockIdx.z;
    const int b = z / nsplit;
    const int sp = z - b * nsplit;
    const AT* A  = Ab + (long)b * sA + (long)sp * Kloop;
    const BT* Bt = Bb + (long)b * sB + (long)sp * Kloop;
    CT* C        = Cb + (long)b * sC;

    __shared__ unsigned short Alds[128 * LDST];
    __shared__ unsigned short Blds[128 * LDST];

    const int tid  = threadIdx.x;
    const int lane = tid & 63;
    const int wave = tid >> 6;            // 0..3
    const int wr   = (wave >> 1) * 64;
    const int wc   = (wave & 1) * 64;
    const int rowBase = blockIdx.x * 128;
    const int colBase = blockIdx.y * 128;
    const int l15  = lane & 15;
    const int quad = lane >> 4;

    f32x4 acc[4][4] = {};

    for (int k0 = 0; k0 < Kloop; k0 += 32) {
        stage_tile(A  + (size_t)rowBase * lda + k0, Alds, lda, tid);
        stage_tile(Bt + (size_t)colBase * ldb + k0, Blds, ldb, tid);
        __syncthreads();

        short8 af[4], bfr[4];
        #pragma unroll
        for (int i = 0; i < 4; ++i) {
            af[i]  = *reinterpret_cast<const short8*>(&Alds[(wr + i * 16 + l15) * LDST + quad * 8]);
            bfr[i] = *reinterpret_cast<const short8*>(&Blds[(wc + i * 16 + l15) * LDST + quad * 8]);
        }
        #pragma unroll
        for (int mi = 0; mi < 4; ++mi)
            #pragma unroll
            for (int ni = 0; ni < 4; ++ni)
                acc[mi][ni] = __builtin_amdgcn_mfma_f32_16x16x32_bf16(
                    af[mi], bfr[ni], acc[mi][ni], 0, 0, 0);
        __syncthreads();
    }

    // C/D layout (m89-verified): col = lane&15, row = quad*4 + reg
    #pragma unroll
    for (int mi = 0; mi < 4; ++mi) {
        #pragma unroll
        for (int ni = 0; ni < 4; ++ni) {
            int col = colBase + wc + ni * 16 + l15;
            #pragma unroll
            for (int r = 0; r < 4; ++r) {
                int row = rowBase + wr + mi * 16 + quad * 4 + r;
                if constexpr (ATOMIC) {
                    unsafeAtomicAdd((float*)&C[(size_t)row * ldc + col], alpha * acc[mi][ni][r]);
                } else {
                    store_c(C, (size_t)row * ldc + col, alpha * acc[mi][ni][r]);
                }
            }
        }
    }
}

extern "C" void kernel_launch(void* const* d_in, const int* in_sizes, int n_in,
                              void* d_out, int out_size, void* d_ws, size_t ws_size,
                              hipStream_t stream)
{
    const float* X  = (const float*)d_in[0];  // [8,2048,768] fp32
    const float* Wq = (const float*)d_in[2];  // [768,768]
    const float* Wk = (const float*)d_in[3];  // [768,768]
    float* out = (float*)d_out;               // [8,2048,768] fp32

    const int Bn = 8, S = 2048, D = 768;
    const float alpha = 1.0f / (768.0f * sqrtf(768.0f));  // 1/768^1.5
    const size_t szXt = (size_t)Bn * S * D;               // elements (ushort)
    const size_t szDD = (size_t)Bn * D * D;

    const size_t need_full = szXt * 2 * 2 + (size_t)D * D * 2 + szDD * 4 + szDD * 2;

    if (ws_size >= need_full) {
        // ---- tier 1: Xt | Xbf | P16 | G32(fp32) | Ht16 ----
        unsigned short* Xt16 = (unsigned short*)d_ws;
        unsigned short* Xbf  = Xt16 + szXt;
        unsigned short* P16  = Xbf + szXt;
        float*          G32  = (float*)(P16 + (size_t)D * D);
        unsigned short* Ht16 = (unsigned short*)(G32 + szDD);

        hipMemsetAsync(G32, 0, szDD * 4, stream);  // graph-capturable

        transpose_bf16<<<dim3(S / 32, D / 32, Bn), 256, 0, stream>>>(X, Xt16, Xbf, S, D);

        // P = Wq * Wk^T
        gemm_abt<float, float, unsigned short, false>
            <<<dim3(6, 6, 1), 256, 0, stream>>>(Wq, Wk, P16, D, D, D,
                                                D, D, D, 0L, 0L, 0L, 1, 1.0f);

        // G32_b += Xt_b[:, sp*512:+512] * (same)^T   (split-K x4, atomic)
        gemm_abt<unsigned short, unsigned short, float, true>
            <<<dim3(6, 6, Bn * 4), 256, 0, stream>>>(Xt16, Xt16, G32, D, D, S / 4,
                                                     S, S, D,
                                                     (long)D * S, (long)D * S, (long)D * D,
                                                     4, 1.0f);

        // Ht_b = alpha * G32_b * P^T   (fp32 A staged->bf16)
        gemm_abt<float, unsigned short, unsigned short, false>
            <<<dim3(6, 6, Bn), 256, 0, stream>>>(G32, P16, Ht16, D, D, D,
                                                 D, D, D,
                                                 (long)D * D, 0L, (long)D * D, 1, alpha);

        // out_b = Xbf_b * Ht_b^T
        gemm_abt<unsigned short, unsigned short, float, false>
            <<<dim3(S / 128, 6, Bn), 256, 0, stream>>>(Xbf, Ht16, out, S, D, D,
                                                       D, D, D,
                                                       (long)S * D, (long)D * D, (long)S * D,
                                                       1, 1.0f);
    } else {
        // ---- fallback tier (R3 layout + pad fix): Xt | P16 | G16 | Ht16 ----
        unsigned short* Xt16 = (unsigned short*)d_ws;
        unsigned short* P16  = Xt16 + szXt;
        unsigned short* G16  = P16 + (size_t)D * D;
        unsigned short* Ht16 = G16 + szDD;
        unsigned short* Xbf  = Xt16;  // unused placeholder for transpose signature

        transpose_bf16<<<dim3(S / 32, D / 32, Bn), 256, 0, stream>>>(X, Xt16, Xbf, S, D);
        // NOTE: Xbf aliases Xt here, but fallback out-GEMM stages A from fp32 X instead.

        gemm_abt<float, float, unsigned short, false>
            <<<dim3(6, 6, 1), 256, 0, stream>>>(Wq, Wk, P16, D, D, D,
                                                D, D, D, 0L, 0L, 0L, 1, 1.0f);
        gemm_abt<unsigned short, unsigned short, unsigned short, false>
            <<<dim3(6, 6, Bn), 256, 0, stream>>>(Xt16, Xt16, G16, D, D, S,
                                                 S, S, D,
                                                 (long)D * S, (long)D * S, (long)D * D, 1, 1.0f);
        gemm_abt<unsigned short, unsigned short, unsigned short, false>
            <<<dim3(6, 6, Bn), 256, 0, stream>>>(G16, P16, Ht16, D, D, D,
                                                 D, D, D,
                                                 (long)D * D, 0L, (long)D * D, 1, alpha);
        gemm_abt<float, unsigned short, float, false>
            <<<dim3(S / 128, 6, Bn), 256, 0, stream>>>(X, Ht16, out, S, D, D,
                                                       D, D, D,
                                                       (long)S * D, (long)D * D, (long)S * D,
                                                       1, 1.0f);
    }
}

// Round 5
// 265.786 us; speedup vs baseline: 1.1191x; 1.1191x over previous
//
#include <hip/hip_runtime.h>
#include <hip/hip_bf16.h>
#include <cmath>

// out[b] = X_b (Wq Wk^T) (X_b^T X_b) / 768^1.5   (47 GF factorized)
//   Pp[2]   = split-K halves of Wq * Wk^T          (fp32 partials, plain stores)
//   Gp[2]_b = split-K halves of Xt_b * Xt_b^T      (fp32 partials, plain stores)
//   Ht_b    = alpha * (Gp0+Gp1)_b * (Pp0+Pp1)^T    (partials summed in staging; bf16 out)
//   out_b   = X_b * Ht_b^T                          (fp32 A staged->bf16, fp32 out)
// MFMA bf16 16x16x32, 128x128 tile, BK=64, fp32 accumulate.
// LDS: [128][64] bf16 per operand (32 KB total), XOR chunk swizzle c^(r&7)
// -> conflict-free under octet service model (R3/R4 counter evidence).

typedef __attribute__((ext_vector_type(8))) short short8;
typedef __attribute__((ext_vector_type(4))) float f32x4;

__device__ __forceinline__ unsigned short f2bf(float f) {
    union { float f; unsigned int u; } v; v.f = f;
    unsigned int u = v.u;
    return (unsigned short)((u + 0x7FFFu + ((u >> 16) & 1u)) >> 16);  // RNE
}

__device__ __forceinline__ uint2 pack4(float4 v) {
    uint2 r;
    r.x = (unsigned)f2bf(v.x) | ((unsigned)f2bf(v.y) << 16);
    r.y = (unsigned)f2bf(v.z) | ((unsigned)f2bf(v.w) << 16);
    return r;
}

// ---- X[b][S][D] fp32 -> Xt[b][D][S] bf16 ----
__global__ __launch_bounds__(256)
void transpose_bf16(const float* __restrict__ X, unsigned short* __restrict__ Xt,
                    int S, int D)
{
    __shared__ unsigned short tile[32][36];
    const int b = blockIdx.z;
    const int s0 = blockIdx.x * 32;
    const int d0 = blockIdx.y * 32;
    const float* Xb = X + (size_t)b * S * D;
    unsigned short* Xtb = Xt + (size_t)b * S * D;
    const int tx = threadIdx.x & 7;    // d-group (4 floats)
    const int ty = threadIdx.x >> 3;   // s 0..31

    float4 v = *reinterpret_cast<const float4*>(&Xb[(size_t)(s0 + ty) * D + d0 + tx * 4]);
    tile[tx * 4 + 0][ty] = f2bf(v.x);
    tile[tx * 4 + 1][ty] = f2bf(v.y);
    tile[tx * 4 + 2][ty] = f2bf(v.z);
    tile[tx * 4 + 3][ty] = f2bf(v.w);
    __syncthreads();
    ushort4 o;
    o.x = tile[ty][tx * 4 + 0];
    o.y = tile[ty][tx * 4 + 1];
    o.z = tile[ty][tx * 4 + 2];
    o.w = tile[ty][tx * 4 + 3];
    *reinterpret_cast<ushort4*>(&Xtb[(size_t)(d0 + ty) * S + s0 + tx * 4]) = o;
}

// ---- staging: 128x64 tile -> LDS [128][64] bf16, chunk-XOR swizzled ----
// KIND 0: bf16 src; 1: fp32 src; 2: sum of two fp32 srcs.
template <int KIND>
__device__ __forceinline__ void stage(const void* p0, const void* p1, long off,
                                      unsigned short* lds, int ld, int tid)
{
    #pragma unroll
    for (int it = 0; it < 4; ++it) {
        int idx = it * 256 + tid;          // 1024 chunks of 16 B
        int r = idx >> 3;
        int c = idx & 7;
        int dst = r * 64 + ((c ^ (r & 7)) * 8);
        if constexpr (KIND == 0) {
            const unsigned short* s = (const unsigned short*)p0 + off;
            uint4 v = *reinterpret_cast<const uint4*>(&s[(size_t)r * ld + c * 8]);
            *reinterpret_cast<uint4*>(&lds[dst]) = v;
        } else if constexpr (KIND == 1) {
            const float* s = (const float*)p0 + off;
            const float* p = &s[(size_t)r * ld + c * 8];
            float4 a = *reinterpret_cast<const float4*>(p);
            float4 b = *reinterpret_cast<const float4*>(p + 4);
            uint2 lo = pack4(a), hi = pack4(b);
            uint4 v; v.x = lo.x; v.y = lo.y; v.z = hi.x; v.w = hi.y;
            *reinterpret_cast<uint4*>(&lds[dst]) = v;
        } else {
            const float* s0 = (const float*)p0 + off;
            const float* s1 = (const float*)p1 + off;
            const float* q0 = &s0[(size_t)r * ld + c * 8];
            const float* q1 = &s1[(size_t)r * ld + c * 8];
            float4 a0 = *reinterpret_cast<const float4*>(q0);
            float4 b0 = *reinterpret_cast<const float4*>(q0 + 4);
            float4 a1 = *reinterpret_cast<const float4*>(q1);
            float4 b1 = *reinterpret_cast<const float4*>(q1 + 4);
            float4 a, b;
            a.x = a0.x + a1.x; a.y = a0.y + a1.y; a.z = a0.z + a1.z; a.w = a0.w + a1.w;
            b.x = b0.x + b1.x; b.y = b0.y + b1.y; b.z = b0.z + b1.z; b.w = b0.w + b1.w;
            uint2 lo = pack4(a), hi = pack4(b);
            uint4 v; v.x = lo.x; v.y = lo.y; v.z = hi.x; v.w = hi.y;
            *reinterpret_cast<uint4*>(&lds[dst]) = v;
        }
    }
}

__device__ __forceinline__ void store_c(float* C, size_t i, float v) { C[i] = v; }
__device__ __forceinline__ void store_c(unsigned short* C, size_t i, float v) { C[i] = f2bf(v); }

// C = alpha * A[M,K_total] * Bt[N,K_total]^T ; row-major; z = b*nsplit + sp.
// Split sp: k in [sp*Kloop*(elements)] via spA pointer offset; C at sp*spC.
template <int AK, int BKIND, typename CT>
__global__ __launch_bounds__(256)
void gemm_abt(const void* __restrict__ Ap, const void* __restrict__ Ap2,
              const void* __restrict__ Bp, const void* __restrict__ Bp2,
              CT* __restrict__ Cb, int Kloop,
              int lda, int ldb, int ldc,
              long sA, long sB, long sC, long spA, long spC,
              int nsplit, float alpha)
{
    const int z = blockIdx.z;
    const int b = z / nsplit;
    const int sp = z - b * nsplit;
    const long aoff = (long)b * sA + (long)sp * spA;
    const long boff = (long)b * sB + (long)sp * spA;
    CT* C = Cb + (long)b * sC + (long)sp * spC;

    __shared__ unsigned short Alds[128 * 64];
    __shared__ unsigned short Blds[128 * 64];

    const int tid  = threadIdx.x;
    const int lane = tid & 63;
    const int wave = tid >> 6;
    const int wr   = (wave >> 1) * 64;
    const int wc   = (wave & 1) * 64;
    const int rowBase = blockIdx.x * 128;
    const int colBase = blockIdx.y * 128;
    const int l15  = lane & 15;
    const int quad = lane >> 4;

    f32x4 acc[4][4] = {};

    for (int k0 = 0; k0 < Kloop; k0 += 64) {
        stage<AK>(Ap, Ap2, aoff + (long)rowBase * lda + k0, Alds, lda, tid);
        stage<BKIND>(Bp, Bp2, boff + (long)colBase * ldb + k0, Blds, ldb, tid);
        __syncthreads();

        short8 af[4][2], bfr[4][2];
        #pragma unroll
        for (int i = 0; i < 4; ++i) {
            int ra = wr + i * 16 + l15;
            int rb = wc + i * 16 + l15;
            af[i][0]  = *reinterpret_cast<const short8*>(&Alds[ra * 64 + ((quad ^ (ra & 7)) * 8)]);
            af[i][1]  = *reinterpret_cast<const short8*>(&Alds[ra * 64 + (((quad + 4) ^ (ra & 7)) * 8)]);
            bfr[i][0] = *reinterpret_cast<const short8*>(&Blds[rb * 64 + ((quad ^ (rb & 7)) * 8)]);
            bfr[i][1] = *reinterpret_cast<const short8*>(&Blds[rb * 64 + (((quad + 4) ^ (rb & 7)) * 8)]);
        }
        #pragma unroll
        for (int ks = 0; ks < 2; ++ks)
            #pragma unroll
            for (int mi = 0; mi < 4; ++mi)
                #pragma unroll
                for (int ni = 0; ni < 4; ++ni)
                    acc[mi][ni] = __builtin_amdgcn_mfma_f32_16x16x32_bf16(
                        af[mi][ks], bfr[ni][ks], acc[mi][ni], 0, 0, 0);
        __syncthreads();
    }

    // C/D layout (m89-verified): col = lane&15, row = quad*4 + reg
    #pragma unroll
    for (int mi = 0; mi < 4; ++mi) {
        #pragma unroll
        for (int ni = 0; ni < 4; ++ni) {
            int col = colBase + wc + ni * 16 + l15;
            #pragma unroll
            for (int r = 0; r < 4; ++r) {
                int row = rowBase + wr + mi * 16 + quad * 4 + r;
                store_c(C, (size_t)row * ldc + col, alpha * acc[mi][ni][r]);
            }
        }
    }
}

extern "C" void kernel_launch(void* const* d_in, const int* in_sizes, int n_in,
                              void* d_out, int out_size, void* d_ws, size_t ws_size,
                              hipStream_t stream)
{
    const float* X  = (const float*)d_in[0];  // [8,2048,768] fp32
    const float* Wq = (const float*)d_in[2];  // [768,768]
    const float* Wk = (const float*)d_in[3];  // [768,768]
    float* out = (float*)d_out;               // [8,2048,768] fp32

    const int Bn = 8, S = 2048, D = 768;
    const float alpha = 1.0f / (768.0f * sqrtf(768.0f));  // 1/768^1.5
    const size_t szXt = (size_t)Bn * S * D;   // ushort elements
    const size_t szDD = (size_t)Bn * D * D;

    // ws layout: Xt16 | Pp(2x fp32 768^2) | Gp(2x fp32 8*768^2) | Ht16  (~77.1 MB)
    unsigned short* Xt16 = (unsigned short*)d_ws;
    float*          Pp   = (float*)(Xt16 + szXt);
    float*          Gp   = Pp + (size_t)2 * D * D;
    unsigned short* Ht16 = (unsigned short*)(Gp + 2 * szDD);

    // Xt_b = X_b^T (bf16)
    transpose_bf16<<<dim3(S / 32, D / 32, Bn), 256, 0, stream>>>(X, Xt16, S, D);

    // Pp[sp] = Wq[:, sp*384:+384] * Wk[:, sp*384:+384]^T  (split-K x2, fp32 partials)
    gemm_abt<1, 1, float><<<dim3(6, 6, 2), 256, 0, stream>>>(
        Wq, nullptr, Wk, nullptr, Pp, 384,
        D, D, D, 0L, 0L, 0L, 384L, (long)D * D, 2, 1.0f);

    // Gp[sp][b] = Xt_b[:, sp*1024:+1024] * (same)^T       (split-K x2, fp32 partials)
    gemm_abt<0, 0, float><<<dim3(6, 6, Bn * 2), 256, 0, stream>>>(
        Xt16, nullptr, Xt16, nullptr, Gp, 1024,
        S, S, D, (long)D * S, (long)D * S, (long)D * D, 1024L, (long)szDD, 2, 1.0f);

    // Ht_b = alpha * (Gp0+Gp1)_b * (Pp0+Pp1)^T            (partial sums in staging)
    gemm_abt<2, 2, unsigned short><<<dim3(6, 6, Bn), 256, 0, stream>>>(
        Gp, Gp + szDD, Pp, Pp + (size_t)D * D, Ht16, 768,
        D, D, D, (long)D * D, 0L, (long)D * D, 0L, 0L, 1, alpha);

    // out_b = X_b * Ht_b^T
    gemm_abt<1, 0, float><<<dim3(S / 128, 6, Bn), 256, 0, stream>>>(
        X, nullptr, Ht16, nullptr, out, 768,
        D, D, D, (long)S * D, (long)D * D, (long)S * D, 0L, 0L, 1, 1.0f);
}

// Round 6
// 214.775 us; speedup vs baseline: 1.3849x; 1.2375x over previous
//
#include <hip/hip_runtime.h>
#include <hip/hip_bf16.h>
#include <cmath>

// out[b] = X_b (Wq Wk^T) (X_b^T X_b) / 768^1.5   (47 GF factorized)
//   P16   = Wq * Wk^T            (fp32 VALU staging, bf16 out; 64x64 tiles, 144 blocks)
//   G16_b = Xt_b * Xt_b^T        (bf16 glds staging; 96x96 tiles, 512 blocks = 2/CU)
//   Ht16_b= alpha * G16_b * P^T  (96x96, 512 blocks)
//   out_b = Xbf_b * Ht16_b^T     (128x128, 768 blocks = 3/CU, fp32 out)
// MFMA bf16 16x16x32, BK=64, fp32 accumulate.
// Staging via __builtin_amdgcn_global_load_lds width=16 (m97 ladder step);
// XOR chunk swizzle retained by permuting the *global* chunk each lane fetches
// (same 128B segment per 8-lane octet -> coalescing intact; fragment reads
// use R5's proven conflict-free addressing).

typedef __attribute__((ext_vector_type(8))) short short8;
typedef __attribute__((ext_vector_type(4))) float f32x4;

__device__ __forceinline__ unsigned short f2bf(float f) {
    union { float f; unsigned int u; } v; v.f = f;
    unsigned int u = v.u;
    return (unsigned short)((u + 0x7FFFu + ((u >> 16) & 1u)) >> 16);  // RNE
}

// ---- X[b][S][D] fp32 -> Xt[b][D][S] bf16 AND Xbf[b][S][D] bf16 ----
__global__ __launch_bounds__(256)
void transpose_bf16(const float* __restrict__ X, unsigned short* __restrict__ Xt,
                    unsigned short* __restrict__ Xbf, int S, int D)
{
    __shared__ unsigned short tile[32][36];
    const int b = blockIdx.z;
    const int s0 = blockIdx.x * 32;
    const int d0 = blockIdx.y * 32;
    const float* Xb = X + (size_t)b * S * D;
    unsigned short* Xtb = Xt + (size_t)b * S * D;
    unsigned short* Xbb = Xbf + (size_t)b * S * D;
    const int tx = threadIdx.x & 7;    // d-group (4 floats)
    const int ty = threadIdx.x >> 3;   // s 0..31

    float4 v = *reinterpret_cast<const float4*>(&Xb[(size_t)(s0 + ty) * D + d0 + tx * 4]);
    ushort4 pk;
    pk.x = f2bf(v.x); pk.y = f2bf(v.y); pk.z = f2bf(v.z); pk.w = f2bf(v.w);
    *reinterpret_cast<ushort4*>(&Xbb[(size_t)(s0 + ty) * D + d0 + tx * 4]) = pk;
    tile[tx * 4 + 0][ty] = pk.x;
    tile[tx * 4 + 1][ty] = pk.y;
    tile[tx * 4 + 2][ty] = pk.z;
    tile[tx * 4 + 3][ty] = pk.w;
    __syncthreads();
    ushort4 o;
    o.x = tile[ty][tx * 4 + 0];
    o.y = tile[ty][tx * 4 + 1];
    o.z = tile[ty][tx * 4 + 2];
    o.w = tile[ty][tx * 4 + 3];
    *reinterpret_cast<ushort4*>(&Xtb[(size_t)(d0 + ty) * S + s0 + tx * 4]) = o;
}

// ---- glds staging: ROWS x 64 bf16 tile -> LDS, 16B chunks, XOR swizzle ----
// LDS slot s (=16B chunk) holds global chunk (r = s>>3, c ^ (r&7)) where c = s&7.
template <int ROWS>
__device__ __forceinline__ void stage_glds(const unsigned short* src, unsigned short* lds,
                                           int ld, int tid)
{
    #pragma unroll
    for (int it = 0; it < ROWS / 32; ++it) {
        int slot = it * 256 + tid;
        int r = slot >> 3, c = slot & 7;
        const unsigned short* gp = src + (size_t)r * ld + ((c ^ (r & 7)) << 3);
        unsigned short* lp = lds + (size_t)(it * 256 + (tid & 192)) * 8;  // wave-uniform base
        __builtin_amdgcn_global_load_lds(
            (__attribute__((address_space(1))) void*)(void*)gp,
            (__attribute__((address_space(3))) void*)lp, 16, 0, 0);
    }
}

// ---- fp32 VALU staging (convert->bf16), same slot/swizzle mapping ----
template <int ROWS>
__device__ __forceinline__ void stage_f32(const float* src, unsigned short* lds,
                                          int ld, int tid)
{
    #pragma unroll
    for (int it = 0; it < ROWS / 32; ++it) {
        int slot = it * 256 + tid;
        int r = slot >> 3, c = slot & 7;
        const float* p = src + (size_t)r * ld + ((c ^ (r & 7)) << 3);
        float4 a = *reinterpret_cast<const float4*>(p);
        float4 b = *reinterpret_cast<const float4*>(p + 4);
        uint4 v;
        v.x = (unsigned)f2bf(a.x) | ((unsigned)f2bf(a.y) << 16);
        v.y = (unsigned)f2bf(a.z) | ((unsigned)f2bf(a.w) << 16);
        v.z = (unsigned)f2bf(b.x) | ((unsigned)f2bf(b.y) << 16);
        v.w = (unsigned)f2bf(b.z) | ((unsigned)f2bf(b.w) << 16);
        *reinterpret_cast<uint4*>(&lds[(size_t)slot * 8]) = v;
    }
}

__device__ __forceinline__ void store_c(float* C, size_t i, float v) { C[i] = v; }
__device__ __forceinline__ void store_c(unsigned short* C, size_t i, float v) { C[i] = f2bf(v); }

// C = alpha * A[M,K] * Bt[N,K]^T ; row-major; batched via blockIdx.z.
template <int TM, int TN, bool AF32, bool BF32, typename CT>
__global__ __launch_bounds__(256)
void gemm(const void* __restrict__ Ap, const void* __restrict__ Bp, CT* __restrict__ Cb,
          int Kloop, int lda, int ldb, int ldc, long sA, long sB, long sC, float alpha)
{
    constexpr int FM = TM / 32;
    constexpr int FN = TN / 32;
    const int b = blockIdx.z;
    CT* C = Cb + (long)b * sC;

    __shared__ unsigned short Alds[TM * 64];
    __shared__ unsigned short Blds[TN * 64];

    const int tid  = threadIdx.x;
    const int lane = tid & 63;
    const int wave = tid >> 6;
    const int wr   = (wave >> 1) * (TM / 2);
    const int wc   = (wave & 1) * (TN / 2);
    const int rowBase = blockIdx.x * TM;
    const int colBase = blockIdx.y * TN;
    const int l15  = lane & 15;
    const int quad = lane >> 4;

    f32x4 acc[FM][FN] = {};

    for (int k0 = 0; k0 < Kloop; k0 += 64) {
        if constexpr (AF32)
            stage_f32<TM>((const float*)Ap + (long)b * sA + (size_t)rowBase * lda + k0,
                          Alds, lda, tid);
        else
            stage_glds<TM>((const unsigned short*)Ap + (long)b * sA + (size_t)rowBase * lda + k0,
                           Alds, lda, tid);
        if constexpr (BF32)
            stage_f32<TN>((const float*)Bp + (long)b * sB + (size_t)colBase * ldb + k0,
                          Blds, ldb, tid);
        else
            stage_glds<TN>((const unsigned short*)Bp + (long)b * sB + (size_t)colBase * ldb + k0,
                           Blds, ldb, tid);
        __syncthreads();

        short8 af[FM][2], bfr[FN][2];
        #pragma unroll
        for (int i = 0; i < FM; ++i) {
            int ra = wr + i * 16 + l15;
            af[i][0] = *reinterpret_cast<const short8*>(&Alds[ra * 64 + ((quad ^ (ra & 7)) << 3)]);
            af[i][1] = *reinterpret_cast<const short8*>(&Alds[ra * 64 + (((quad + 4) ^ (ra & 7)) << 3)]);
        }
        #pragma unroll
        for (int i = 0; i < FN; ++i) {
            int rb = wc + i * 16 + l15;
            bfr[i][0] = *reinterpret_cast<const short8*>(&Blds[rb * 64 + ((quad ^ (rb & 7)) << 3)]);
            bfr[i][1] = *reinterpret_cast<const short8*>(&Blds[rb * 64 + (((quad + 4) ^ (rb & 7)) << 3)]);
        }
        #pragma unroll
        for (int ks = 0; ks < 2; ++ks)
            #pragma unroll
            for (int mi = 0; mi < FM; ++mi)
                #pragma unroll
                for (int ni = 0; ni < FN; ++ni)
                    acc[mi][ni] = __builtin_amdgcn_mfma_f32_16x16x32_bf16(
                        af[mi][ks], bfr[ni][ks], acc[mi][ni], 0, 0, 0);
        __syncthreads();
    }

    // C/D layout (m89-verified): col = lane&15, row = quad*4 + reg
    #pragma unroll
    for (int mi = 0; mi < FM; ++mi) {
        #pragma unroll
        for (int ni = 0; ni < FN; ++ni) {
            int col = colBase + wc + ni * 16 + l15;
            #pragma unroll
            for (int r = 0; r < 4; ++r) {
                int row = rowBase + wr + mi * 16 + quad * 4 + r;
                store_c(C, (size_t)row * ldc + col, alpha * acc[mi][ni][r]);
            }
        }
    }
}

extern "C" void kernel_launch(void* const* d_in, const int* in_sizes, int n_in,
                              void* d_out, int out_size, void* d_ws, size_t ws_size,
                              hipStream_t stream)
{
    const float* X  = (const float*)d_in[0];  // [8,2048,768] fp32
    const float* Wq = (const float*)d_in[2];  // [768,768]
    const float* Wk = (const float*)d_in[3];  // [768,768]
    float* out = (float*)d_out;               // [8,2048,768] fp32

    const int Bn = 8, S = 2048, D = 768;
    const float alpha = 1.0f / (768.0f * sqrtf(768.0f));  // 1/768^1.5
    const size_t szX  = (size_t)Bn * S * D;   // ushort elements
    const size_t szDD = (size_t)Bn * D * D;

    // ws: Xt16 | Xbf | P16 | G16 | Ht16  (~70.4 MB, all bf16)
    unsigned short* Xt16 = (unsigned short*)d_ws;
    unsigned short* Xbf  = Xt16 + szX;
    unsigned short* P16  = Xbf + szX;
    unsigned short* G16  = P16 + (size_t)D * D;
    unsigned short* Ht16 = G16 + szDD;

    transpose_bf16<<<dim3(S / 32, D / 32, Bn), 256, 0, stream>>>(X, Xt16, Xbf, S, D);

    // P = Wq * Wk^T   (fp32 in, bf16 out; 64x64 tiles for grid width)
    gemm<64, 64, true, true, unsigned short><<<dim3(12, 12, 1), 256, 0, stream>>>(
        Wq, Wk, P16, D, D, D, D, 0L, 0L, 0L, 1.0f);

    // G_b = Xt_b * Xt_b^T   (K = 2048; 8x8x8 = 512 blocks = 2/CU)
    gemm<96, 96, false, false, unsigned short><<<dim3(8, 8, Bn), 256, 0, stream>>>(
        Xt16, Xt16, G16, S, S, S, D, (long)D * S, (long)D * S, (long)D * D, 1.0f);

    // Ht_b = alpha * G_b * P^T  (== H^T since G symmetric)
    gemm<96, 96, false, false, unsigned short><<<dim3(8, 8, Bn), 256, 0, stream>>>(
        G16, P16, Ht16, D, D, D, D, (long)D * D, 0L, (long)D * D, alpha);

    // out_b = Xbf_b * Ht_b^T   (16x6x8 = 768 blocks = 3/CU)
    gemm<128, 128, false, false, float><<<dim3(S / 128, 6, Bn), 256, 0, stream>>>(
        Xbf, Ht16, out, D, D, D, D, (long)S * D, (long)D * D, (long)S * D, 1.0f);
}

// Round 7
// 189.853 us; speedup vs baseline: 1.5667x; 1.1313x over previous
//
#include <hip/hip_runtime.h>
#include <hip/hip_bf16.h>
#include <cmath>

// out[b] = X_b (Wq Wk^T) (X_b^T X_b) / 768^1.5   (47 GF factorized)
//   W16    = bf16(Wq), bf16(Wk)       (convert kernel)
//   P16    = Wq16 * Wk16^T            (glds staging; 64x64 tiles)
//   G16_b  = Xt_b * Xt_b^T            (96x96; batch-pinned to XCD: Xt_b=3.15MB < 4MB L2)
//   Ht16_b = alpha * G16_b * P^T      (96x96, batch-pinned)
//   out_b  = Xbf_b * Ht16_b^T         (128x128, batch-pinned, fp32 out)
// MFMA bf16 16x16x32, BK=64, fp32 accumulate, glds width-16 staging,
// XOR chunk swizzle (bank-conflict-free, verified R5/R6: SQ_LDS_BANK_CONFLICT=0).
// Batch in blockIdx.x => XCD = b%8 under round-robin dispatch => per-XCD
// working set L2-resident => HBM fetch ~= compulsory.

typedef __attribute__((ext_vector_type(8))) short short8;
typedef __attribute__((ext_vector_type(4))) float f32x4;

__device__ __forceinline__ unsigned short f2bf(float f) {
    union { float f; unsigned int u; } v; v.f = f;
    unsigned int u = v.u;
    return (unsigned short)((u + 0x7FFFu + ((u >> 16) & 1u)) >> 16);  // RNE
}

// ---- Wq,Wk fp32 -> bf16 ----
__global__ __launch_bounds__(256)
void convert_w(const float* __restrict__ Wq, const float* __restrict__ Wk,
               unsigned short* __restrict__ Wq16, unsigned short* __restrict__ Wk16)
{
    int i = (blockIdx.x * 256 + threadIdx.x) * 8;   // 768*768 / 8 = 73728 threads
    float4 a = *reinterpret_cast<const float4*>(&Wq[i]);
    float4 b = *reinterpret_cast<const float4*>(&Wq[i + 4]);
    uint4 v;
    v.x = (unsigned)f2bf(a.x) | ((unsigned)f2bf(a.y) << 16);
    v.y = (unsigned)f2bf(a.z) | ((unsigned)f2bf(a.w) << 16);
    v.z = (unsigned)f2bf(b.x) | ((unsigned)f2bf(b.y) << 16);
    v.w = (unsigned)f2bf(b.z) | ((unsigned)f2bf(b.w) << 16);
    *reinterpret_cast<uint4*>(&Wq16[i]) = v;
    a = *reinterpret_cast<const float4*>(&Wk[i]);
    b = *reinterpret_cast<const float4*>(&Wk[i + 4]);
    v.x = (unsigned)f2bf(a.x) | ((unsigned)f2bf(a.y) << 16);
    v.y = (unsigned)f2bf(a.z) | ((unsigned)f2bf(a.w) << 16);
    v.z = (unsigned)f2bf(b.x) | ((unsigned)f2bf(b.y) << 16);
    v.w = (unsigned)f2bf(b.z) | ((unsigned)f2bf(b.w) << 16);
    *reinterpret_cast<uint4*>(&Wk16[i]) = v;
}

// ---- X[b][S][D] fp32 -> Xt[b][D][S] bf16 AND Xbf[b][S][D] bf16 ----
__global__ __launch_bounds__(256)
void transpose_bf16(const float* __restrict__ X, unsigned short* __restrict__ Xt,
                    unsigned short* __restrict__ Xbf, int S, int D)
{
    __shared__ unsigned short tile[32][36];
    const int b = blockIdx.z;
    const int s0 = blockIdx.x * 32;
    const int d0 = blockIdx.y * 32;
    const float* Xb = X + (size_t)b * S * D;
    unsigned short* Xtb = Xt + (size_t)b * S * D;
    unsigned short* Xbb = Xbf + (size_t)b * S * D;
    const int tx = threadIdx.x & 7;    // d-group (4 floats)
    const int ty = threadIdx.x >> 3;   // s 0..31

    float4 v = *reinterpret_cast<const float4*>(&Xb[(size_t)(s0 + ty) * D + d0 + tx * 4]);
    ushort4 pk;
    pk.x = f2bf(v.x); pk.y = f2bf(v.y); pk.z = f2bf(v.z); pk.w = f2bf(v.w);
    *reinterpret_cast<ushort4*>(&Xbb[(size_t)(s0 + ty) * D + d0 + tx * 4]) = pk;
    tile[tx * 4 + 0][ty] = pk.x;
    tile[tx * 4 + 1][ty] = pk.y;
    tile[tx * 4 + 2][ty] = pk.z;
    tile[tx * 4 + 3][ty] = pk.w;
    __syncthreads();
    ushort4 o;
    o.x = tile[ty][tx * 4 + 0];
    o.y = tile[ty][tx * 4 + 1];
    o.z = tile[ty][tx * 4 + 2];
    o.w = tile[ty][tx * 4 + 3];
    *reinterpret_cast<ushort4*>(&Xtb[(size_t)(d0 + ty) * S + s0 + tx * 4]) = o;
}

// ---- glds staging: ROWS x 64 bf16 tile -> LDS, 16B chunks, XOR swizzle ----
template <int ROWS>
__device__ __forceinline__ void stage_glds(const unsigned short* src, unsigned short* lds,
                                           int ld, int tid)
{
    #pragma unroll
    for (int it = 0; it < ROWS / 32; ++it) {
        int slot = it * 256 + tid;
        int r = slot >> 3, c = slot & 7;
        const unsigned short* gp = src + (size_t)r * ld + ((c ^ (r & 7)) << 3);
        unsigned short* lp = lds + (size_t)(it * 256 + (tid & 192)) * 8;  // wave-uniform base
        __builtin_amdgcn_global_load_lds(
            (__attribute__((address_space(1))) void*)(void*)gp,
            (__attribute__((address_space(3))) void*)lp, 16, 0, 0);
    }
}

__device__ __forceinline__ void store_c(float* C, size_t i, float v) { C[i] = v; }
__device__ __forceinline__ void store_c(unsigned short* C, size_t i, float v) { C[i] = f2bf(v); }

// C = alpha * A[M,K] * Bt[N,K]^T ; row-major.
// Grid = (batch, rowTiles, colTiles): batch in blockIdx.x pins batch->XCD (b%8).
template <int TM, int TN, typename CT>
__global__ __launch_bounds__(256)
void gemm(const unsigned short* __restrict__ Ap, const unsigned short* __restrict__ Bp,
          CT* __restrict__ Cb,
          int Kloop, int lda, int ldb, int ldc, long sA, long sB, long sC, float alpha)
{
    constexpr int FM = TM / 32;
    constexpr int FN = TN / 32;
    const int b = blockIdx.x;
    CT* C = Cb + (long)b * sC;

    __shared__ unsigned short Alds[TM * 64];
    __shared__ unsigned short Blds[TN * 64];

    const int tid  = threadIdx.x;
    const int lane = tid & 63;
    const int wave = tid >> 6;
    const int wr   = (wave >> 1) * (TM / 2);
    const int wc   = (wave & 1) * (TN / 2);
    const int rowBase = blockIdx.y * TM;
    const int colBase = blockIdx.z * TN;
    const int l15  = lane & 15;
    const int quad = lane >> 4;

    f32x4 acc[FM][FN] = {};

    for (int k0 = 0; k0 < Kloop; k0 += 64) {
        stage_glds<TM>(Ap + (long)b * sA + (size_t)rowBase * lda + k0, Alds, lda, tid);
        stage_glds<TN>(Bp + (long)b * sB + (size_t)colBase * ldb + k0, Blds, ldb, tid);
        __syncthreads();

        short8 af[FM][2], bfr[FN][2];
        #pragma unroll
        for (int i = 0; i < FM; ++i) {
            int ra = wr + i * 16 + l15;
            af[i][0] = *reinterpret_cast<const short8*>(&Alds[ra * 64 + ((quad ^ (ra & 7)) << 3)]);
            af[i][1] = *reinterpret_cast<const short8*>(&Alds[ra * 64 + (((quad + 4) ^ (ra & 7)) << 3)]);
        }
        #pragma unroll
        for (int i = 0; i < FN; ++i) {
            int rb = wc + i * 16 + l15;
            bfr[i][0] = *reinterpret_cast<const short8*>(&Blds[rb * 64 + ((quad ^ (rb & 7)) << 3)]);
            bfr[i][1] = *reinterpret_cast<const short8*>(&Blds[rb * 64 + (((quad + 4) ^ (rb & 7)) << 3)]);
        }
        #pragma unroll
        for (int ks = 0; ks < 2; ++ks)
            #pragma unroll
            for (int mi = 0; mi < FM; ++mi)
                #pragma unroll
                for (int ni = 0; ni < FN; ++ni)
                    acc[mi][ni] = __builtin_amdgcn_mfma_f32_16x16x32_bf16(
                        af[mi][ks], bfr[ni][ks], acc[mi][ni], 0, 0, 0);
        __syncthreads();
    }

    // C/D layout (m89-verified): col = lane&15, row = quad*4 + reg
    #pragma unroll
    for (int mi = 0; mi < FM; ++mi) {
        #pragma unroll
        for (int ni = 0; ni < FN; ++ni) {
            int col = colBase + wc + ni * 16 + l15;
            #pragma unroll
            for (int r = 0; r < 4; ++r) {
                int row = rowBase + wr + mi * 16 + quad * 4 + r;
                store_c(C, (size_t)row * ldc + col, alpha * acc[mi][ni][r]);
            }
        }
    }
}

extern "C" void kernel_launch(void* const* d_in, const int* in_sizes, int n_in,
                              void* d_out, int out_size, void* d_ws, size_t ws_size,
                              hipStream_t stream)
{
    const float* X  = (const float*)d_in[0];  // [8,2048,768] fp32
    const float* Wq = (const float*)d_in[2];  // [768,768]
    const float* Wk = (const float*)d_in[3];  // [768,768]
    float* out = (float*)d_out;               // [8,2048,768] fp32

    const int Bn = 8, S = 2048, D = 768;
    const float alpha = 1.0f / (768.0f * sqrtf(768.0f));  // 1/768^1.5
    const size_t szX  = (size_t)Bn * S * D;   // ushort elements
    const size_t szDD = (size_t)Bn * D * D;

    // ws: Xt16 | Xbf | P16 | G16 | Ht16 | Wq16 | Wk16  (~72.9 MB)
    unsigned short* Xt16 = (unsigned short*)d_ws;
    unsigned short* Xbf  = Xt16 + szX;
    unsigned short* P16  = Xbf + szX;
    unsigned short* G16  = P16 + (size_t)D * D;
    unsigned short* Ht16 = G16 + szDD;
    unsigned short* Wq16 = Ht16 + szDD;
    unsigned short* Wk16 = Wq16 + (size_t)D * D;

    convert_w<<<dim3(D * D / 2048, 1, 1), 256, 0, stream>>>(Wq, Wk, Wq16, Wk16);

    transpose_bf16<<<dim3(S / 32, D / 32, Bn), 256, 0, stream>>>(X, Xt16, Xbf, S, D);

    // P = Wq16 * Wk16^T   (grid (1,12,12))
    gemm<64, 64, unsigned short><<<dim3(1, 12, 12), 256, 0, stream>>>(
        Wq16, Wk16, P16, D, D, D, D, 0L, 0L, 0L, 1.0f);

    // G_b = Xt_b * Xt_b^T   (K = 2048; batch-pinned grid (8,8,8))
    gemm<96, 96, unsigned short><<<dim3(Bn, 8, 8), 256, 0, stream>>>(
        Xt16, Xt16, G16, S, S, S, D, (long)D * S, (long)D * S, (long)D * D, 1.0f);

    // Ht_b = alpha * G_b * P^T  (== H^T since G symmetric; batch-pinned)
    gemm<96, 96, unsigned short><<<dim3(Bn, 8, 8), 256, 0, stream>>>(
        G16, P16, Ht16, D, D, D, D, (long)D * D, 0L, (long)D * D, alpha);

    // out_b = Xbf_b * Ht_b^T   (batch-pinned grid (8,16,6))
    gemm<128, 128, float><<<dim3(Bn, S / 128, 6), 256, 0, stream>>>(
        Xbf, Ht16, out, D, D, D, D, (long)S * D, (long)D * D, (long)S * D, 1.0f);
}